// Round 2
// baseline (191.929 us; speedup 1.0000x reference)
//
#include <hip/hip_runtime.h>
#include <hip/hip_bf16.h>

// Problem constants (from reference setup_inputs)
#define BDIM 256     // batch
#define NDIM 1152    // route nodes
#define CIN 8
#define KDIM 10      // num capsule groups
#define COUT 16
#define NTHREADS 256
#define NPT 18       // n values per lane = NDIM / 64

// Block = one (k,b). 4 waves per block; wave wv owns co = wv*4 .. wv*4+3.
// Lane l owns n = l + 64*j, j = 0..17. pred lives entirely in registers
// (p[18][4] = 72 VGPR). No LDS, no __syncthreads.
__global__ __launch_bounds__(NTHREADS)
void capsule_routing_kernel(const float* __restrict__ x,      // [B, N, CIN]
                            const float* __restrict__ w,      // [K, N, CIN, COUT]
                            const int*   __restrict__ niter_p,
                            float*       __restrict__ out)    // [K, B, COUT]
{
    const int blk = blockIdx.x;           // k * BDIM + b  (k outer => L2 reuse of W[k])
    const int k = blk >> 8;               // BDIM == 256
    const int b = blk & (BDIM - 1);
    const int t  = threadIdx.x;
    const int wv = t >> 6;                // wave id = co quad
    const int l  = t & 63;                // lane

    const float* __restrict__ xb = x + (size_t)b * NDIM * CIN;
    const float* __restrict__ wk = w + (size_t)k * NDIM * CIN * COUT + wv * 4;

    float p[NPT][4];
    float psum[4] = {0.f, 0.f, 0.f, 0.f};
    float pmax[4], pmin[4];
#pragma unroll
    for (int c = 0; c < 4; ++c) { pmax[c] = -3.4e38f; pmin[c] = 3.4e38f; }

    // -------- Phase 1 (fused stats): p[j][c] = sum_i x[b,n,i] * W[k,n,i,co] --------
#pragma unroll
    for (int j = 0; j < NPT; ++j) {
        const int n = l + 64 * j;
        const float4 xa = *reinterpret_cast<const float4*>(xb + n * CIN);
        const float4 xc = *reinterpret_cast<const float4*>(xb + n * CIN + 4);
        const float xs[8] = {xa.x, xa.y, xa.z, xa.w, xc.x, xc.y, xc.z, xc.w};
        const float* wr = wk + n * CIN * COUT;
        float acc[4] = {0.f, 0.f, 0.f, 0.f};
#pragma unroll
        for (int i = 0; i < CIN; ++i) {
            const float4 wv4 = *reinterpret_cast<const float4*>(wr + i * COUT);
            acc[0] = fmaf(xs[i], wv4.x, acc[0]);
            acc[1] = fmaf(xs[i], wv4.y, acc[1]);
            acc[2] = fmaf(xs[i], wv4.z, acc[2]);
            acc[3] = fmaf(xs[i], wv4.w, acc[3]);
        }
#pragma unroll
        for (int c = 0; c < 4; ++c) {
            p[j][c] = acc[c];
            psum[c] += acc[c];
            pmax[c] = fmaxf(pmax[c], acc[c]);
            pmin[c] = fminf(pmin[c], acc[c]);
        }
    }

    // -------- wave-wide reduce of stats (64 lanes) --------
#pragma unroll
    for (int m = 1; m < 64; m <<= 1) {
#pragma unroll
        for (int c = 0; c < 4; ++c) {
            psum[c] += __shfl_xor(psum[c], m, 64);
            pmax[c] = fmaxf(pmax[c], __shfl_xor(pmax[c], m, 64));
            pmin[c] = fminf(pmin[c], __shfl_xor(pmin[c], m, 64));
        }
    }

    const int niter = *niter_p;

    // Iteration 1: logits == 0 -> softmax uniform -> s = mean_n(pred)
    float s[4], v[4], vc[4];
#pragma unroll
    for (int c = 0; c < 4; ++c) {
        s[c]  = psum[c] * (1.0f / (float)NDIM);
        v[c]  = s[c] * fabsf(s[c]) / (1.f + s[c] * s[c]);  // squash (singleton dim)
        vc[c] = v[c];                                      // logits = pred * vc
    }

    for (int it = 1; it < niter; ++it) {
        float m4[4], se[4] = {0.f,0.f,0.f,0.f}, sp[4] = {0.f,0.f,0.f,0.f};
#pragma unroll
        for (int c = 0; c < 4; ++c)
            m4[c] = (vc[c] >= 0.f) ? vc[c] * pmax[c] : vc[c] * pmin[c];
#pragma unroll
        for (int j = 0; j < NPT; ++j) {
#pragma unroll
            for (int c = 0; c < 4; ++c) {
                const float e = __expf(p[j][c] * vc[c] - m4[c]);
                se[c] += e;
                sp[c] += e * p[j][c];
            }
        }
#pragma unroll
        for (int m = 1; m < 64; m <<= 1) {
#pragma unroll
            for (int c = 0; c < 4; ++c) {
                se[c] += __shfl_xor(se[c], m, 64);
                sp[c] += __shfl_xor(sp[c], m, 64);
            }
        }
#pragma unroll
        for (int c = 0; c < 4; ++c) {
            s[c]  = sp[c] / se[c];
            v[c]  = s[c] * fabsf(s[c]) / (1.f + s[c] * s[c]);
            vc[c] += v[c];
        }
    }

    if (l == 0) {
        float4 o;
        o.x = v[0]; o.y = v[1]; o.z = v[2]; o.w = v[3];
        *reinterpret_cast<float4*>(out + (size_t)blk * COUT + wv * 4) = o;
    }
}

extern "C" void kernel_launch(void* const* d_in, const int* in_sizes, int n_in,
                              void* d_out, int out_size, void* d_ws, size_t ws_size,
                              hipStream_t stream) {
    const float* x = (const float*)d_in[0];
    const float* w = (const float*)d_in[1];
    const int* niter = (const int*)d_in[2];
    float* out = (float*)d_out;

    const int grid = KDIM * BDIM;   // 2560 blocks, k outer
    capsule_routing_kernel<<<grid, NTHREADS, 0, stream>>>(x, w, niter, out);
}

// Round 3
// 189.355 us; speedup vs baseline: 1.0136x; 1.0136x over previous
//
#include <hip/hip_runtime.h>
#include <hip/hip_bf16.h>

// Problem constants (from reference setup_inputs)
#define BDIM 256     // batch
#define NDIM 1152    // route nodes
#define CIN 8
#define KDIM 10      // num capsule groups
#define COUT 16
#define NTHREADS 512
#define NHALF 576    // NDIM / 2
#define NPT 9        // n values per lane = NHALF / 64

// Block = one (k,b). 8 waves = 4 co-quads x 2 n-halves.
// Wave (q,h): co = q*4..q*4+3, n = h*576 + l + 64*j (j=0..8).
// pred slice lives in registers: p[9][4] = 36 VGPR/thread.
// Cross-half reduction via tiny LDS buffer.
__global__ __launch_bounds__(NTHREADS, 4)
void capsule_routing_kernel(const float* __restrict__ x,      // [B, N, CIN]
                            const float* __restrict__ w,      // [K, N, CIN, COUT]
                            const int*   __restrict__ niter_p,
                            float*       __restrict__ out)    // [K, B, COUT]
{
    __shared__ float redS[2][4][3][4];   // [half][quad][stat: sum,max,min][c]
    __shared__ float redI[2][4][2][4];   // [half][quad][stat: se,sp][c]

    const int blk = blockIdx.x;          // k * BDIM + b (k outer => L2 reuse of W[k])
    const int k = blk >> 8;              // BDIM == 256
    const int b = blk & (BDIM - 1);
    const int t  = threadIdx.x;
    const int wv = t >> 6;
    const int q  = wv & 3;               // co quad
    const int h  = wv >> 2;              // n half
    const int l  = t & 63;

    const float* __restrict__ xb = x + ((size_t)b * NDIM + h * NHALF) * CIN;
    const float* __restrict__ wk = w + ((size_t)k * NDIM + h * NHALF) * CIN * COUT + q * 4;

    float p[NPT][4];
    float psum[4] = {0.f, 0.f, 0.f, 0.f};
    float pmax[4], pmin[4];
#pragma unroll
    for (int c = 0; c < 4; ++c) { pmax[c] = -3.4e38f; pmin[c] = 3.4e38f; }

    // -------- Phase 1 (fused stats): p[j][c] = sum_i x[b,n,i] * W[k,n,i,co] --------
#pragma unroll
    for (int j = 0; j < NPT; ++j) {
        const int n = l + 64 * j;                 // local n within half
        const float4 xa = *reinterpret_cast<const float4*>(xb + n * CIN);
        const float4 xc = *reinterpret_cast<const float4*>(xb + n * CIN + 4);
        const float xs[8] = {xa.x, xa.y, xa.z, xa.w, xc.x, xc.y, xc.z, xc.w};
        const float* wr = wk + n * CIN * COUT;    // CIN*COUT = 128
        float acc[4] = {0.f, 0.f, 0.f, 0.f};
#pragma unroll
        for (int i = 0; i < CIN; ++i) {
            const float4 w4 = *reinterpret_cast<const float4*>(wr + i * COUT);
            acc[0] = fmaf(xs[i], w4.x, acc[0]);
            acc[1] = fmaf(xs[i], w4.y, acc[1]);
            acc[2] = fmaf(xs[i], w4.z, acc[2]);
            acc[3] = fmaf(xs[i], w4.w, acc[3]);
        }
#pragma unroll
        for (int c = 0; c < 4; ++c) {
            p[j][c] = acc[c];
            psum[c] += acc[c];
            pmax[c] = fmaxf(pmax[c], acc[c]);
            pmin[c] = fminf(pmin[c], acc[c]);
        }
    }

    // -------- wave-wide reduce (64 lanes over this half's n) --------
#pragma unroll
    for (int m = 1; m < 64; m <<= 1) {
#pragma unroll
        for (int c = 0; c < 4; ++c) {
            psum[c] += __shfl_xor(psum[c], m, 64);
            pmax[c] = fmaxf(pmax[c], __shfl_xor(pmax[c], m, 64));
            pmin[c] = fminf(pmin[c], __shfl_xor(pmin[c], m, 64));
        }
    }
    if (l == 0) {
#pragma unroll
        for (int c = 0; c < 4; ++c) {
            redS[h][q][0][c] = psum[c];
            redS[h][q][1][c] = pmax[c];
            redS[h][q][2][c] = pmin[c];
        }
    }
    __syncthreads();
#pragma unroll
    for (int c = 0; c < 4; ++c) {
        psum[c] = redS[0][q][0][c] + redS[1][q][0][c];
        pmax[c] = fmaxf(redS[0][q][1][c], redS[1][q][1][c]);
        pmin[c] = fminf(redS[0][q][2][c], redS[1][q][2][c]);
    }

    const int niter = *niter_p;

    // Iteration 1: logits == 0 -> softmax uniform -> s = mean_n(pred)
    float s[4], v[4], vc[4];
#pragma unroll
    for (int c = 0; c < 4; ++c) {
        s[c]  = psum[c] * (1.0f / (float)NDIM);
        v[c]  = s[c] * fabsf(s[c]) / (1.f + s[c] * s[c]);  // squash (singleton dim)
        vc[c] = v[c];                                      // logits = pred * vc
    }

    for (int it = 1; it < niter; ++it) {
        float m4[4], se[4] = {0.f,0.f,0.f,0.f}, sp[4] = {0.f,0.f,0.f,0.f};
#pragma unroll
        for (int c = 0; c < 4; ++c)
            m4[c] = (vc[c] >= 0.f) ? vc[c] * pmax[c] : vc[c] * pmin[c];
#pragma unroll
        for (int j = 0; j < NPT; ++j) {
#pragma unroll
            for (int c = 0; c < 4; ++c) {
                const float e = __expf(p[j][c] * vc[c] - m4[c]);
                se[c] += e;
                sp[c] += e * p[j][c];
            }
        }
#pragma unroll
        for (int m = 1; m < 64; m <<= 1) {
#pragma unroll
            for (int c = 0; c < 4; ++c) {
                se[c] += __shfl_xor(se[c], m, 64);
                sp[c] += __shfl_xor(sp[c], m, 64);
            }
        }
        __syncthreads();   // protect redI reads from previous iteration
        if (l == 0) {
#pragma unroll
            for (int c = 0; c < 4; ++c) {
                redI[h][q][0][c] = se[c];
                redI[h][q][1][c] = sp[c];
            }
        }
        __syncthreads();
#pragma unroll
        for (int c = 0; c < 4; ++c) {
            const float seT = redI[0][q][0][c] + redI[1][q][0][c];
            const float spT = redI[0][q][1][c] + redI[1][q][1][c];
            s[c]  = spT / seT;
            v[c]  = s[c] * fabsf(s[c]) / (1.f + s[c] * s[c]);
            vc[c] += v[c];
        }
    }

    if (h == 0 && l == 0) {
        float4 o;
        o.x = v[0]; o.y = v[1]; o.z = v[2]; o.w = v[3];
        *reinterpret_cast<float4*>(out + (size_t)blk * COUT + q * 4) = o;
    }
}

extern "C" void kernel_launch(void* const* d_in, const int* in_sizes, int n_in,
                              void* d_out, int out_size, void* d_ws, size_t ws_size,
                              hipStream_t stream) {
    const float* x = (const float*)d_in[0];
    const float* w = (const float*)d_in[1];
    const int* niter = (const int*)d_in[2];
    float* out = (float*)d_out;

    const int grid = KDIM * BDIM;   // 2560 blocks, k outer
    capsule_routing_kernel<<<grid, NTHREADS, 0, stream>>>(x, w, niter, out);
}

// Round 4
// 73.244 us; speedup vs baseline: 2.6204x; 2.5853x over previous
//
#include <hip/hip_runtime.h>
#include <hip/hip_bf16.h>

// Problem constants (from reference setup_inputs)
#define BDIM 256     // batch
#define NDIM 1152    // route nodes
#define CIN 8
#define KDIM 10      // num capsule groups
#define COUT 16
#define NTHREADS 512
#define BT 2         // batches per block (b-tile) -> W[k] read once for 2 b's
#define NPT 9        // n values per thread = NDIM / (NTHREADS/4)

// Block = (k, b-pair). 512 threads; thread t owns co-quad coq=t&3 for
// n = (t>>2) + 128*j, j=0..8, for BOTH batches of the pair.
// pred stored as packed bf16x2 in LDS [BT][NDIM][8] uints (73.7 KB):
//  - W loads: float4, 4 coq-lanes cover each 64B line exactly once (16 lines/instr)
//  - LDS read/write: byte addr == 8*lane pattern -> conflict-free
// Cross-thread softmax reductions: shfl_xor (masks 4..32, coq-invariant) + small LDS.

__device__ __forceinline__ unsigned f2bf(float f) {       // RNE f32 -> bf16 bits
    unsigned u = __float_as_uint(f);
    return (u + 0x7fffu + ((u >> 16) & 1u)) >> 16;
}
__device__ __forceinline__ float bf_lo(unsigned u) { return __uint_as_float(u << 16); }
__device__ __forceinline__ float bf_hi(unsigned u) { return __uint_as_float(u & 0xffff0000u); }

__global__ __launch_bounds__(NTHREADS, 4)
void capsule_routing_kernel(const float* __restrict__ x,      // [B, N, CIN]
                            const float* __restrict__ w,      // [K, N, CIN, COUT]
                            const int*   __restrict__ niter_p,
                            float*       __restrict__ out)    // [K, B, COUT]
{
    __shared__ unsigned predS[BT][NDIM][COUT / 2];   // bf16x2, 73728 B
    __shared__ float red[8][4][24];                  // [wave][coq][stats], 3 KB

    const int blk = blockIdx.x;
    const int k   = blk >> 7;                 // / (BDIM/BT) == 128
    const int bp  = blk & 127;
    const int b0  = bp * BT;
    const int t   = threadIdx.x;
    const int wv  = t >> 6;
    const int l   = t & 63;
    const int coq = t & 3;                    // co quad: co = coq*4 .. coq*4+3
    const int nb  = t >> 2;                   // base n (0..127)

    const float* __restrict__ xb0 = x + (size_t)b0 * NDIM * CIN;
    const float* __restrict__ xb1 = xb0 + NDIM * CIN;
    const float* __restrict__ wk  = w + (size_t)k * NDIM * CIN * COUT + coq * 4;

    float psum[BT][4] = {{0.f,0.f,0.f,0.f},{0.f,0.f,0.f,0.f}};
    float pmax[BT][4], pmin[BT][4];
#pragma unroll
    for (int bb = 0; bb < BT; ++bb)
#pragma unroll
        for (int c = 0; c < 4; ++c) { pmax[bb][c] = -3.4e38f; pmin[bb][c] = 3.4e38f; }

    // -------- Phase 1: pred (both b's) + fused per-thread stats --------
#pragma unroll
    for (int j = 0; j < NPT; ++j) {
        const int n = nb + 128 * j;
        const float4 xa0 = *reinterpret_cast<const float4*>(xb0 + n * CIN);
        const float4 xc0 = *reinterpret_cast<const float4*>(xb0 + n * CIN + 4);
        const float4 xa1 = *reinterpret_cast<const float4*>(xb1 + n * CIN);
        const float4 xc1 = *reinterpret_cast<const float4*>(xb1 + n * CIN + 4);
        const float xs0[8] = {xa0.x, xa0.y, xa0.z, xa0.w, xc0.x, xc0.y, xc0.z, xc0.w};
        const float xs1[8] = {xa1.x, xa1.y, xa1.z, xa1.w, xc1.x, xc1.y, xc1.z, xc1.w};
        const float* wr = wk + (size_t)n * (CIN * COUT);
        float a0[4] = {0.f,0.f,0.f,0.f};
        float a1[4] = {0.f,0.f,0.f,0.f};
#pragma unroll
        for (int i = 0; i < CIN; ++i) {
            const float4 w4 = *reinterpret_cast<const float4*>(wr + i * COUT);
            a0[0] = fmaf(xs0[i], w4.x, a0[0]);
            a0[1] = fmaf(xs0[i], w4.y, a0[1]);
            a0[2] = fmaf(xs0[i], w4.z, a0[2]);
            a0[3] = fmaf(xs0[i], w4.w, a0[3]);
            a1[0] = fmaf(xs1[i], w4.x, a1[0]);
            a1[1] = fmaf(xs1[i], w4.y, a1[1]);
            a1[2] = fmaf(xs1[i], w4.z, a1[2]);
            a1[3] = fmaf(xs1[i], w4.w, a1[3]);
        }
        // pack to bf16, stats on the ROUNDED values (consistent with later reads)
        const unsigned q00 = f2bf(a0[0]) | (f2bf(a0[1]) << 16);
        const unsigned q01 = f2bf(a0[2]) | (f2bf(a0[3]) << 16);
        const unsigned q10 = f2bf(a1[0]) | (f2bf(a1[1]) << 16);
        const unsigned q11 = f2bf(a1[2]) | (f2bf(a1[3]) << 16);
        predS[0][n][coq * 2]     = q00;
        predS[0][n][coq * 2 + 1] = q01;
        predS[1][n][coq * 2]     = q10;
        predS[1][n][coq * 2 + 1] = q11;
        const float r0[4] = {bf_lo(q00), bf_hi(q00), bf_lo(q01), bf_hi(q01)};
        const float r1[4] = {bf_lo(q10), bf_hi(q10), bf_lo(q11), bf_hi(q11)};
#pragma unroll
        for (int c = 0; c < 4; ++c) {
            psum[0][c] += r0[c];
            pmax[0][c] = fmaxf(pmax[0][c], r0[c]);
            pmin[0][c] = fminf(pmin[0][c], r0[c]);
            psum[1][c] += r1[c];
            pmax[1][c] = fmaxf(pmax[1][c], r1[c]);
            pmin[1][c] = fminf(pmin[1][c], r1[c]);
        }
    }

    // -------- stats reduce: within wave over the 16 lanes sharing coq --------
#pragma unroll
    for (int m = 4; m < 64; m <<= 1) {
#pragma unroll
        for (int bb = 0; bb < BT; ++bb)
#pragma unroll
            for (int c = 0; c < 4; ++c) {
                psum[bb][c] += __shfl_xor(psum[bb][c], m, 64);
                pmax[bb][c] = fmaxf(pmax[bb][c], __shfl_xor(pmax[bb][c], m, 64));
                pmin[bb][c] = fminf(pmin[bb][c], __shfl_xor(pmin[bb][c], m, 64));
            }
    }
    if (l < 4) {   // lane l holds group coq == l
#pragma unroll
        for (int bb = 0; bb < BT; ++bb)
#pragma unroll
            for (int c = 0; c < 4; ++c) {
                red[wv][l][bb * 4 + c]      = psum[bb][c];
                red[wv][l][8 + bb * 4 + c]  = pmax[bb][c];
                red[wv][l][16 + bb * 4 + c] = pmin[bb][c];
            }
    }
    __syncthreads();
#pragma unroll
    for (int bb = 0; bb < BT; ++bb)
#pragma unroll
        for (int c = 0; c < 4; ++c) { psum[bb][c] = 0.f; pmax[bb][c] = -3.4e38f; pmin[bb][c] = 3.4e38f; }
    for (int wvi = 0; wvi < 8; ++wvi) {
#pragma unroll
        for (int bb = 0; bb < BT; ++bb)
#pragma unroll
            for (int c = 0; c < 4; ++c) {
                psum[bb][c] += red[wvi][coq][bb * 4 + c];
                pmax[bb][c] = fmaxf(pmax[bb][c], red[wvi][coq][8 + bb * 4 + c]);
                pmin[bb][c] = fminf(pmin[bb][c], red[wvi][coq][16 + bb * 4 + c]);
            }
    }

    const int niter = *niter_p;

    // Iteration 1: logits == 0 -> uniform softmax -> s = mean_n(pred)
    float v[BT][4], vc[BT][4];
#pragma unroll
    for (int bb = 0; bb < BT; ++bb)
#pragma unroll
        for (int c = 0; c < 4; ++c) {
            const float s = psum[bb][c] * (1.0f / (float)NDIM);
            v[bb][c]  = s * fabsf(s) / (1.f + s * s);   // squash (singleton dim)
            vc[bb][c] = v[bb][c];                        // logits = pred * vc
        }

    for (int it = 1; it < niter; ++it) {
        float m4[BT][4], se[BT][4] = {{0,0,0,0},{0,0,0,0}}, sp[BT][4] = {{0,0,0,0},{0,0,0,0}};
#pragma unroll
        for (int bb = 0; bb < BT; ++bb)
#pragma unroll
            for (int c = 0; c < 4; ++c)
                m4[bb][c] = (vc[bb][c] >= 0.f) ? vc[bb][c] * pmax[bb][c] : vc[bb][c] * pmin[bb][c];

#pragma unroll
        for (int j = 0; j < NPT; ++j) {
            const int n = nb + 128 * j;
            const uint2 q0 = *reinterpret_cast<const uint2*>(&predS[0][n][coq * 2]);
            const uint2 q1 = *reinterpret_cast<const uint2*>(&predS[1][n][coq * 2]);
            const float p0[4] = {bf_lo(q0.x), bf_hi(q0.x), bf_lo(q0.y), bf_hi(q0.y)};
            const float p1[4] = {bf_lo(q1.x), bf_hi(q1.x), bf_lo(q1.y), bf_hi(q1.y)};
#pragma unroll
            for (int c = 0; c < 4; ++c) {
                const float e0 = __expf(fmaf(p0[c], vc[0][c], -m4[0][c]));
                se[0][c] += e0;
                sp[0][c] = fmaf(e0, p0[c], sp[0][c]);
                const float e1 = __expf(fmaf(p1[c], vc[1][c], -m4[1][c]));
                se[1][c] += e1;
                sp[1][c] = fmaf(e1, p1[c], sp[1][c]);
            }
        }
#pragma unroll
        for (int m = 4; m < 64; m <<= 1) {
#pragma unroll
            for (int bb = 0; bb < BT; ++bb)
#pragma unroll
                for (int c = 0; c < 4; ++c) {
                    se[bb][c] += __shfl_xor(se[bb][c], m, 64);
                    sp[bb][c] += __shfl_xor(sp[bb][c], m, 64);
                }
        }
        __syncthreads();   // previous red readers done before overwrite
        if (l < 4) {
#pragma unroll
            for (int bb = 0; bb < BT; ++bb)
#pragma unroll
                for (int c = 0; c < 4; ++c) {
                    red[wv][l][bb * 4 + c]     = se[bb][c];
                    red[wv][l][8 + bb * 4 + c] = sp[bb][c];
                }
        }
        __syncthreads();
#pragma unroll
        for (int bb = 0; bb < BT; ++bb)
#pragma unroll
            for (int c = 0; c < 4; ++c) {
                float seT = 0.f, spT = 0.f;
                for (int wvi = 0; wvi < 8; ++wvi) {
                    seT += red[wvi][coq][bb * 4 + c];
                    spT += red[wvi][coq][8 + bb * 4 + c];
                }
                const float s = spT / seT;
                v[bb][c]  = s * fabsf(s) / (1.f + s * s);
                vc[bb][c] += v[bb][c];
            }
    }

    if (t < 4) {   // coq == t
#pragma unroll
        for (int bb = 0; bb < BT; ++bb) {
            float4 o;
            o.x = v[bb][0]; o.y = v[bb][1]; o.z = v[bb][2]; o.w = v[bb][3];
            *reinterpret_cast<float4*>(out + ((size_t)k * BDIM + b0 + bb) * COUT + t * 4) = o;
        }
    }
}

extern "C" void kernel_launch(void* const* d_in, const int* in_sizes, int n_in,
                              void* d_out, int out_size, void* d_ws, size_t ws_size,
                              hipStream_t stream) {
    const float* x = (const float*)d_in[0];
    const float* w = (const float*)d_in[1];
    const int* niter = (const int*)d_in[2];
    float* out = (float*)d_out;

    const int grid = KDIM * (BDIM / BT);   // 1280 blocks, k outer
    capsule_routing_kernel<<<grid, NTHREADS, 0, stream>>>(x, w, niter, out);
}